// Round 5
// baseline (105.060 us; speedup 1.0000x reference)
//
#include <hip/hip_runtime.h>

// Chamfer distance, B=8, N=M=8192, D=3, fp32 — fused MFMA, TWO-PASS form.
// Each fp32 split into f16 hi+lo (x = xh+xl, err ~2^-22). K=16 vectors:
//   A(n): [ah0,ah1,ah2, al0,al1,al2, ah0,ah1,ah2, sqh_n,sql_n, 1,1, 0,0,0]
//   B(m): [bh0,bh1,bh2, bh0,bh1,bh2, bl0,bl1,bl2, 1,1, sqh_m,sql_m, 0,0,0]
// with b = -2c (exact scale). One v_mfma_f32_32x32x16_f16 yields a 32x32
// tile of d(n,m) = sq_n + sq_m - 2<a,c> (+O(1e-5)).
// C/D: col=lane&31, row=(reg&3)+8*(reg>>2)+4*(lane>>5)  [HW-verified]
// A/B: row/col=lane&31, k=(lane>>5)*8+j                 [verified: absmax 0]
//
// LDS layout: B-frag for (cand i, part p) at element (i>>5)*512 + p*256 +
// (i&31)*8, so lane l of tile t reads byte t*1024 + l*16 — linear in lane,
// conflict-free (round-2 PMC: SQ_LDS_BANK_CONFLICT == 0).
//
// Round-5 structure: chamfer is role-symmetric, so dist2 is computed as a
// ROW-min in a second pass with A/B pointers swapped (pass = blockIdx.y/MH)
// using the identical dist1-only inner loop. This deletes the entire
// per-tile column-min path (colmin16, cross-half shfls, d2w planes, fold
// phase) that was ~55% of round-3's VALU+DS budget. Inner loop is the
// round-3-proven code minus dist2; no inline asm (round-4 suspect).

typedef _Float16 half8 __attribute__((ext_vector_type(8)));
typedef float    f16x  __attribute__((ext_vector_type(16)));

constexpr int B       = 8;
constexpr int NPTS    = 8192;
constexpr int TOTAL   = B * NPTS;        // 65536
constexpr int NSTRIP  = 256;             // A-rows per block (8 waves * 32)
constexpr int NSTRIPS = NPTS / NSTRIP;   // 32
constexpr int MH      = 4;               // B-range splits per batch
constexpr int MHALF   = NPTS / MH;       // 2048
constexpr int CHUNK   = 512;             // B-points staged in LDS per chunk
constexpr int NCHUNK  = MHALF / CHUNK;   // 4

// Pack one point into the B-operand (hi,lo) fragment pair.
__device__ __forceinline__ void packB(float cx, float cy, float cz,
                                      half8& plo, half8& phi)
{
    float x = -2.f * cx, y = -2.f * cy, z = -2.f * cz;
    float sq = fmaf(cx, cx, fmaf(cy, cy, cz * cz));
    _Float16 xh = (_Float16)x, yh = (_Float16)y, zh = (_Float16)z;
    _Float16 xl = (_Float16)(x - (float)xh);
    _Float16 yl = (_Float16)(y - (float)yh);
    _Float16 zl = (_Float16)(z - (float)zh);
    _Float16 sh = (_Float16)sq, sl = (_Float16)(sq - (float)sh);
    plo = half8{xh, yh, zh, xh, yh, zh, xl, yl};
    phi = half8{zl, (_Float16)1.f, (_Float16)1.f, sh, sl,
                (_Float16)0.f, (_Float16)0.f, (_Float16)0.f};
}

// grid (32, 8, 8): y = pass*MH + mh. Block 512 (8 waves x 32 A-rows).
// Row-min over this block's 2048-col range -> minp[pass][b][mh][row]
// (unclamped; clamp happens after the cross-plane fold in reduce).
__global__ __launch_bounds__(512, 8) void nn_mfma(
    const float* __restrict__ in1, const float* __restrict__ in2,
    float* __restrict__ minp, float* __restrict__ out)
{
    const int b     = blockIdx.z;
    const int strip = blockIdx.x;
    const int pass  = blockIdx.y / MH;
    const int mh    = blockIdx.y % MH;
    const int wave  = threadIdx.x >> 6;
    const int lane  = threadIdx.x & 63;
    const int col   = lane & 31;
    const int half  = lane >> 5;

    const float* Apts = pass ? in2 : in1;
    const float* Bpts = pass ? in1 : in2;

    if ((blockIdx.x | blockIdx.y | blockIdx.z) == 0 && threadIdx.x == 0)
        *out = 0.0f;                   // zero accumulator before reduce runs

    __shared__ _Float16 ldsB[CHUNK * 16];      // 16 KiB

    // A fragment, packed in-register.
    const int nbase = strip * NSTRIP + wave * 32;
    half8 afrag;
    {
        const float* a = Apts + ((size_t)b * NPTS + nbase + col) * 3;
        float x = a[0], y = a[1], z = a[2];
        float sq = fmaf(x, x, fmaf(y, y, z * z));
        _Float16 xh = (_Float16)x, yh = (_Float16)y, zh = (_Float16)z;
        _Float16 xl = (_Float16)(x - (float)xh);
        _Float16 yl = (_Float16)(y - (float)yh);
        _Float16 zl = (_Float16)(z - (float)zh);
        _Float16 sh = (_Float16)sq, sl = (_Float16)(sq - (float)sh);
        half8 lo = {xh, yh, zh, xl, yl, zl, xh, yh};
        half8 hi = {zh, sh, sl, (_Float16)1.f, (_Float16)1.f,
                    (_Float16)0.f, (_Float16)0.f, (_Float16)0.f};
        afrag = half ? hi : lo;
    }

    f16x MN1, zacc;
#pragma unroll
    for (int r = 0; r < 16; ++r) { MN1[r] = 1e30f; zacc[r] = 0.0f; }

    const float* Craw = Bpts + ((size_t)b * NPTS + mh * MHALF) * 3;

    // Prefetch chunk 0's raw candidate into registers.
    float px, py, pz;
    {
        const float* cp = Craw + (size_t)threadIdx.x * 3;
        px = cp[0]; py = cp[1]; pz = cp[2];
    }

    for (int c = 0; c < NCHUNK; ++c) {
        // Pack this chunk's candidate (register-only, pre-barrier).
        half8 plo, phi;
        packB(px, py, pz, plo, phi);
        __syncthreads();    // prev compute done: ldsB free
        *(half8*)&ldsB[(threadIdx.x >> 5) * 512 + (threadIdx.x & 31) * 8]       = plo;
        *(half8*)&ldsB[(threadIdx.x >> 5) * 512 + 256 + (threadIdx.x & 31) * 8] = phi;
        // Issue next chunk's raw load now; latency hides under compute.
        if (c + 1 < NCHUNK) {
            const float* cp = Craw + (size_t)((c + 1) * CHUNK + threadIdx.x) * 3;
            px = cp[0]; py = cp[1]; pz = cp[2];
        }
        __syncthreads();    // ldsB ready

#pragma unroll
        for (int t = 0; t < CHUNK / 32; t += 2) {
            half8 bfA = *(const half8*)&ldsB[ t      * 512 + lane * 8];
            half8 bfB = *(const half8*)&ldsB[(t + 1) * 512 + lane * 8];
            f16x accA = __builtin_amdgcn_mfma_f32_32x32x16_f16(afrag, bfA, zacc, 0, 0, 0);
            f16x accB = __builtin_amdgcn_mfma_f32_32x32x16_f16(afrag, bfB, zacc, 0, 0, 0);

            // row-min: per-reg running min across cols (v_min3 per reg).
#pragma unroll
            for (int r = 0; r < 16; ++r)
                MN1[r] = fminf(fminf(accA[r], accB[r]), MN1[r]);
        }
    }

    // Butterfly min across the 32 cols of each half, lane 0 of each half
    // writes its 16 rows: row = (r&3) + 8*(r>>2) + 4*half.
#pragma unroll
    for (int m = 1; m <= 16; m <<= 1)
#pragma unroll
        for (int r = 0; r < 16; ++r)
            MN1[r] = fminf(MN1[r], __shfl_xor(MN1[r], m, 64));
    if (col == 0) {
        float* o = minp + (((size_t)pass * B + b) * MH + mh) * NPTS + nbase;
#pragma unroll
        for (int r = 0; r < 16; ++r)
            o[(r & 3) + 8 * (r >> 2) + 4 * half] = MN1[r];
    }
}

// One thread per 4 rows: fold MH planes from each pass (float4), clamp,
// sum, wave-reduce, atomicAdd(out, sum/TOTAL).
__global__ __launch_bounds__(64) void reduce_kernel(
    const float* __restrict__ minp, float* __restrict__ out)
{
    int g  = blockIdx.x * 64 + threadIdx.x;       // [0, TOTAL/4)
    int b  = g >> 11;
    int mq = g & 2047;                            // float4 index within batch

    float v = 0.0f;
#pragma unroll
    for (int p = 0; p < 2; ++p) {
        const float4* pp =
            (const float4*)(minp + (((size_t)p * B + b) * MH) * NPTS) + mq;
        float4 a = pp[0];
#pragma unroll
        for (int s = 1; s < MH; ++s) {
            float4 t = pp[(size_t)s * (NPTS / 4)];
            a.x = fminf(a.x, t.x); a.y = fminf(a.y, t.y);
            a.z = fminf(a.z, t.z); a.w = fminf(a.w, t.w);
        }
        v += fmaxf(a.x, 0.0f) + fmaxf(a.y, 0.0f)
           + fmaxf(a.z, 0.0f) + fmaxf(a.w, 0.0f);
    }

#pragma unroll
    for (int off = 32; off; off >>= 1)
        v += __shfl_down(v, off, 64);
    if (threadIdx.x == 0)
        atomicAdd(out, v * (1.0f / (float)TOTAL));
}

extern "C" void kernel_launch(void* const* d_in, const int* in_sizes, int n_in,
                              void* d_out, int out_size, void* d_ws, size_t ws_size,
                              hipStream_t stream)
{
    const float* in1 = (const float*)d_in[0];
    const float* in2 = (const float*)d_in[1];
    float* out = (float*)d_out;

    float* minp = (float*)d_ws;    // 2 passes * MH * TOTAL * 4 = 2 MiB

    nn_mfma<<<dim3(NSTRIPS, 2 * MH, B), 512, 0, stream>>>(
        in1, in2, minp, out);
    reduce_kernel<<<TOTAL / 4 / 64, 64, 0, stream>>>(minp, out);
}

// Round 6
// 104.846 us; speedup vs baseline: 1.0020x; 1.0020x over previous
//
#include <hip/hip_runtime.h>

// Chamfer distance, B=8, N=M=8192, D=3, fp32 — fused MFMA, TWO-PASS form.
// Each fp32 split into f16 hi+lo (x = xh+xl, err ~2^-22). K=16 vectors:
//   A(n): [ah0,ah1,ah2, al0,al1,al2, ah0,ah1,ah2, sqh_n,sql_n, 1,1, 0,0,0]
//   B(m): [bh0,bh1,bh2, bh0,bh1,bh2, bl0,bl1,bl2, 1,1, sqh_m,sql_m, 0,0,0]
// with b = -2c (exact scale). One v_mfma_f32_32x32x16_f16 yields a 32x32
// tile of d(n,m) = sq_n + sq_m - 2<a,c> (+O(1e-5)).
// C/D: col=lane&31, row=(reg&3)+8*(reg>>2)+4*(lane>>5)  [HW-verified]
// A/B: row/col=lane&31, k=(lane>>5)*8+j                 [verified: absmax 0]
//
// LDS layout: B-frag for (cand i, part p) at element (i>>5)*512 + p*256 +
// (i&31)*8, so lane l of tile t reads byte t*1024 + l*16 — linear in lane,
// conflict-free (round-2 PMC: SQ_LDS_BANK_CONFLICT == 0).
//
// Round-6 change: AGPR-shuffle elimination. All prior rounds showed
// VGPR_Count=32 with a ~100-reg live set -> compiler kept MFMA accums in
// AGPRs and paid v_accvgpr_read/write per min-fold (~60 VALU/iter measured
// vs ~20 ideal; dur tracked VALU-busy in every round). Empty inline-asm
// "+v" pins force acc/MN1/zacc into arch VGPRs (gfx950 unified file: MFMA
// D may be VGPR); __launch_bounds__(512,4) gives the 128-reg budget.

typedef _Float16 half8 __attribute__((ext_vector_type(8)));
typedef float    f16x  __attribute__((ext_vector_type(16)));

#define PIN_V(x) asm volatile("" : "+v"(x))

constexpr int B       = 8;
constexpr int NPTS    = 8192;
constexpr int TOTAL   = B * NPTS;        // 65536
constexpr int NSTRIP  = 256;             // A-rows per block (8 waves * 32)
constexpr int NSTRIPS = NPTS / NSTRIP;   // 32
constexpr int MH      = 4;               // B-range splits per batch
constexpr int MHALF   = NPTS / MH;       // 2048
constexpr int CHUNK   = 512;             // B-points staged in LDS per chunk
constexpr int NCHUNK  = MHALF / CHUNK;   // 4

// Pack one point into the B-operand (hi,lo) fragment pair.
__device__ __forceinline__ void packB(float cx, float cy, float cz,
                                      half8& plo, half8& phi)
{
    float x = -2.f * cx, y = -2.f * cy, z = -2.f * cz;
    float sq = fmaf(cx, cx, fmaf(cy, cy, cz * cz));
    _Float16 xh = (_Float16)x, yh = (_Float16)y, zh = (_Float16)z;
    _Float16 xl = (_Float16)(x - (float)xh);
    _Float16 yl = (_Float16)(y - (float)yh);
    _Float16 zl = (_Float16)(z - (float)zh);
    _Float16 sh = (_Float16)sq, sl = (_Float16)(sq - (float)sh);
    plo = half8{xh, yh, zh, xh, yh, zh, xl, yl};
    phi = half8{zl, (_Float16)1.f, (_Float16)1.f, sh, sl,
                (_Float16)0.f, (_Float16)0.f, (_Float16)0.f};
}

// grid (32, 8, 8): y = pass*MH + mh. Block 512 (8 waves x 32 A-rows).
// Row-min over this block's 2048-col range -> minp[pass][b][mh][row]
// (unclamped; clamp happens after the cross-plane fold in reduce).
__global__ __launch_bounds__(512, 4) void nn_mfma(
    const float* __restrict__ in1, const float* __restrict__ in2,
    float* __restrict__ minp, float* __restrict__ out)
{
    const int b     = blockIdx.z;
    const int strip = blockIdx.x;
    const int pass  = blockIdx.y / MH;
    const int mh    = blockIdx.y % MH;
    const int wave  = threadIdx.x >> 6;
    const int lane  = threadIdx.x & 63;
    const int col   = lane & 31;
    const int half  = lane >> 5;

    const float* Apts = pass ? in2 : in1;
    const float* Bpts = pass ? in1 : in2;

    if ((blockIdx.x | blockIdx.y | blockIdx.z) == 0 && threadIdx.x == 0)
        *out = 0.0f;                   // zero accumulator before reduce runs

    __shared__ _Float16 ldsB[CHUNK * 16];      // 16 KiB

    // A fragment, packed in-register.
    const int nbase = strip * NSTRIP + wave * 32;
    half8 afrag;
    {
        const float* a = Apts + ((size_t)b * NPTS + nbase + col) * 3;
        float x = a[0], y = a[1], z = a[2];
        float sq = fmaf(x, x, fmaf(y, y, z * z));
        _Float16 xh = (_Float16)x, yh = (_Float16)y, zh = (_Float16)z;
        _Float16 xl = (_Float16)(x - (float)xh);
        _Float16 yl = (_Float16)(y - (float)yh);
        _Float16 zl = (_Float16)(z - (float)zh);
        _Float16 sh = (_Float16)sq, sl = (_Float16)(sq - (float)sh);
        half8 lo = {xh, yh, zh, xl, yl, zl, xh, yh};
        half8 hi = {zh, sh, sl, (_Float16)1.f, (_Float16)1.f,
                    (_Float16)0.f, (_Float16)0.f, (_Float16)0.f};
        afrag = half ? hi : lo;
    }

    f16x MN1, zacc;
#pragma unroll
    for (int r = 0; r < 16; ++r) { MN1[r] = 1e30f; zacc[r] = 0.0f; }
    PIN_V(MN1);    // force arch-VGPR class (not AGPR) for the running min
    PIN_V(zacc);   // and the zero C-operand

    const float* Craw = Bpts + ((size_t)b * NPTS + mh * MHALF) * 3;

    // Prefetch chunk 0's raw candidate into registers.
    float px, py, pz;
    {
        const float* cp = Craw + (size_t)threadIdx.x * 3;
        px = cp[0]; py = cp[1]; pz = cp[2];
    }

    for (int c = 0; c < NCHUNK; ++c) {
        // Pack this chunk's candidate (register-only, pre-barrier).
        half8 plo, phi;
        packB(px, py, pz, plo, phi);
        __syncthreads();    // prev compute done: ldsB free
        *(half8*)&ldsB[(threadIdx.x >> 5) * 512 + (threadIdx.x & 31) * 8]       = plo;
        *(half8*)&ldsB[(threadIdx.x >> 5) * 512 + 256 + (threadIdx.x & 31) * 8] = phi;
        // Issue next chunk's raw load now; latency hides under compute.
        if (c + 1 < NCHUNK) {
            const float* cp = Craw + (size_t)((c + 1) * CHUNK + threadIdx.x) * 3;
            px = cp[0]; py = cp[1]; pz = cp[2];
        }
        __syncthreads();    // ldsB ready

#pragma unroll
        for (int t = 0; t < CHUNK / 32; t += 2) {
            half8 bfA = *(const half8*)&ldsB[ t      * 512 + lane * 8];
            half8 bfB = *(const half8*)&ldsB[(t + 1) * 512 + lane * 8];
            f16x accA = __builtin_amdgcn_mfma_f32_32x32x16_f16(afrag, bfA, zacc, 0, 0, 0);
            f16x accB = __builtin_amdgcn_mfma_f32_32x32x16_f16(afrag, bfB, zacc, 0, 0, 0);
            PIN_V(accA);   // MFMA D in VGPRs -> min-fold reads need no
            PIN_V(accB);   // v_accvgpr_read cross-file moves

            // row-min: per-reg running min across cols (v_min3 per reg).
#pragma unroll
            for (int r = 0; r < 16; ++r)
                MN1[r] = fminf(fminf(accA[r], accB[r]), MN1[r]);
        }
    }

    // Butterfly min across the 32 cols of each half, lane 0 of each half
    // writes its 16 rows: row = (r&3) + 8*(r>>2) + 4*half.
#pragma unroll
    for (int m = 1; m <= 16; m <<= 1)
#pragma unroll
        for (int r = 0; r < 16; ++r)
            MN1[r] = fminf(MN1[r], __shfl_xor(MN1[r], m, 64));
    if (col == 0) {
        float* o = minp + (((size_t)pass * B + b) * MH + mh) * NPTS + nbase;
#pragma unroll
        for (int r = 0; r < 16; ++r)
            o[(r & 3) + 8 * (r >> 2) + 4 * half] = MN1[r];
    }
}

// One thread per 4 rows: fold MH planes from each pass (float4), clamp,
// sum, wave-reduce, atomicAdd(out, sum/TOTAL).
__global__ __launch_bounds__(64) void reduce_kernel(
    const float* __restrict__ minp, float* __restrict__ out)
{
    int g  = blockIdx.x * 64 + threadIdx.x;       // [0, TOTAL/4)
    int b  = g >> 11;
    int mq = g & 2047;                            // float4 index within batch

    float v = 0.0f;
#pragma unroll
    for (int p = 0; p < 2; ++p) {
        const float4* pp =
            (const float4*)(minp + (((size_t)p * B + b) * MH) * NPTS) + mq;
        float4 a = pp[0];
#pragma unroll
        for (int s = 1; s < MH; ++s) {
            float4 t = pp[(size_t)s * (NPTS / 4)];
            a.x = fminf(a.x, t.x); a.y = fminf(a.y, t.y);
            a.z = fminf(a.z, t.z); a.w = fminf(a.w, t.w);
        }
        v += fmaxf(a.x, 0.0f) + fmaxf(a.y, 0.0f)
           + fmaxf(a.z, 0.0f) + fmaxf(a.w, 0.0f);
    }

#pragma unroll
    for (int off = 32; off; off >>= 1)
        v += __shfl_down(v, off, 64);
    if (threadIdx.x == 0)
        atomicAdd(out, v * (1.0f / (float)TOTAL));
}

extern "C" void kernel_launch(void* const* d_in, const int* in_sizes, int n_in,
                              void* d_out, int out_size, void* d_ws, size_t ws_size,
                              hipStream_t stream)
{
    const float* in1 = (const float*)d_in[0];
    const float* in2 = (const float*)d_in[1];
    float* out = (float*)d_out;

    float* minp = (float*)d_ws;    // 2 passes * MH * TOTAL * 4 = 2 MiB

    nn_mfma<<<dim3(NSTRIPS, 2 * MH, B), 512, 0, stream>>>(
        in1, in2, minp, out);
    reduce_kernel<<<TOTAL / 4 / 64, 64, 0, stream>>>(minp, out);
}

// Round 7
// 100.303 us; speedup vs baseline: 1.0474x; 1.0453x over previous
//
#include <hip/hip_runtime.h>

// Chamfer distance, B=8, N=M=8192, D=3, fp32 — fused MFMA, TWO-PASS form.
// Each fp32 split into f16 hi+lo (x = xh+xl, err ~2^-22). K=16 vectors:
//   A(n): [ah0,ah1,ah2, al0,al1,al2, ah0,ah1,ah2, sqh_n,sql_n, 1,1, 0,0,0]
//   B(m): [bh0,bh1,bh2, bh0,bh1,bh2, bl0,bl1,bl2, 1,1, sqh_m,sql_m, 0,0,0]
// with b = -2c (exact scale). One v_mfma_f32_32x32x16_f16 yields a 32x32
// tile of d(n,m) = sq_n + sq_m - 2<a,c> (+O(1e-5)).
// C/D: col=lane&31, row=(reg&3)+8*(reg>>2)+4*(lane>>5)  [HW-verified]
// A/B: row/col=lane&31, k=(lane>>5)*8+j                 [verified: absmax 0]
//
// LDS layout: B-frag for (cand i, part p) at element (i>>5)*512 + p*256 +
// (i&31)*8, so lane l of tile t reads byte t*1024 + l*16 — linear in lane,
// conflict-free (round-2 PMC: SQ_LDS_BANK_CONFLICT == 0).
//
// Round-7 change: DS-pipe diet. Counter model: DS pipe was ~61K cyc/CU
// (1 ds_read_b128 per MFMA at ~12 cyc) vs 33K MFMA — the binding pipe in
// every round so far. Fix: A-reuse x2 (each wave owns 2 A-frags = 64 rows;
// per bf0/bf1 pair read -> 4 MFMAs) halves DS-reads-per-MFMA; CHUNK
// 512->1024 (32 KiB LDS) halves barrier count. Structure otherwise
// byte-identical to the round-5 PASSING kernel (no pins, no inline asm).

typedef _Float16 half8 __attribute__((ext_vector_type(8)));
typedef float    f16x  __attribute__((ext_vector_type(16)));

constexpr int B       = 8;
constexpr int NPTS    = 8192;
constexpr int TOTAL   = B * NPTS;        // 65536
constexpr int NSTRIP  = 512;             // A-rows per block (8 waves * 64)
constexpr int NSTRIPS = NPTS / NSTRIP;   // 16
constexpr int MH      = 4;               // B-range splits per batch
constexpr int MHALF   = NPTS / MH;       // 2048
constexpr int CHUNK   = 1024;            // B-points staged in LDS per chunk
constexpr int NCHUNK  = MHALF / CHUNK;   // 2

// Pack one point into the B-operand (hi,lo) fragment pair.
__device__ __forceinline__ void packB(float cx, float cy, float cz,
                                      half8& plo, half8& phi)
{
    float x = -2.f * cx, y = -2.f * cy, z = -2.f * cz;
    float sq = fmaf(cx, cx, fmaf(cy, cy, cz * cz));
    _Float16 xh = (_Float16)x, yh = (_Float16)y, zh = (_Float16)z;
    _Float16 xl = (_Float16)(x - (float)xh);
    _Float16 yl = (_Float16)(y - (float)yh);
    _Float16 zl = (_Float16)(z - (float)zh);
    _Float16 sh = (_Float16)sq, sl = (_Float16)(sq - (float)sh);
    plo = half8{xh, yh, zh, xh, yh, zh, xl, yl};
    phi = half8{zl, (_Float16)1.f, (_Float16)1.f, sh, sl,
                (_Float16)0.f, (_Float16)0.f, (_Float16)0.f};
}

// grid (16, 8, 8): y = pass*MH + mh. Block 512 (8 waves x 64 A-rows).
// Row-min over this block's 2048-col range -> minp[pass][b][mh][row]
// (unclamped; clamp happens after the cross-plane fold in reduce).
__global__ __launch_bounds__(512, 4) void nn_mfma(
    const float* __restrict__ in1, const float* __restrict__ in2,
    float* __restrict__ minp, float* __restrict__ out)
{
    const int b     = blockIdx.z;
    const int strip = blockIdx.x;
    const int pass  = blockIdx.y / MH;
    const int mh    = blockIdx.y % MH;
    const int wave  = threadIdx.x >> 6;
    const int lane  = threadIdx.x & 63;
    const int col   = lane & 31;
    const int half  = lane >> 5;

    const float* Apts = pass ? in2 : in1;
    const float* Bpts = pass ? in1 : in2;

    if ((blockIdx.x | blockIdx.y | blockIdx.z) == 0 && threadIdx.x == 0)
        *out = 0.0f;                   // zero accumulator before reduce runs

    __shared__ _Float16 ldsB[CHUNK * 16];      // 32 KiB

    // TWO A fragments per wave (rows nbase..+31 and nbase+32..+63).
    const int nbase = strip * NSTRIP + wave * 64;
    half8 afrag0, afrag1;
#pragma unroll
    for (int s = 0; s < 2; ++s) {
        const float* a = Apts + ((size_t)b * NPTS + nbase + s * 32 + col) * 3;
        float x = a[0], y = a[1], z = a[2];
        float sq = fmaf(x, x, fmaf(y, y, z * z));
        _Float16 xh = (_Float16)x, yh = (_Float16)y, zh = (_Float16)z;
        _Float16 xl = (_Float16)(x - (float)xh);
        _Float16 yl = (_Float16)(y - (float)yh);
        _Float16 zl = (_Float16)(z - (float)zh);
        _Float16 sh = (_Float16)sq, sl = (_Float16)(sq - (float)sh);
        half8 lo = {xh, yh, zh, xl, yl, zl, xh, yh};
        half8 hi = {zh, sh, sl, (_Float16)1.f, (_Float16)1.f,
                    (_Float16)0.f, (_Float16)0.f, (_Float16)0.f};
        if (s == 0) afrag0 = half ? hi : lo;
        else        afrag1 = half ? hi : lo;
    }

    f16x MN1a, MN1b, zacc;
#pragma unroll
    for (int r = 0; r < 16; ++r) { MN1a[r] = 1e30f; MN1b[r] = 1e30f; zacc[r] = 0.0f; }

    const float* Craw = Bpts + ((size_t)b * NPTS + mh * MHALF) * 3;

    // Prefetch chunk 0's raw candidates (2 per thread) into registers.
    float px0, py0, pz0, px1, py1, pz1;
    {
        const float* cp = Craw + (size_t)threadIdx.x * 3;
        px0 = cp[0]; py0 = cp[1]; pz0 = cp[2];
        const float* cq = Craw + (size_t)(512 + threadIdx.x) * 3;
        px1 = cq[0]; py1 = cq[1]; pz1 = cq[2];
    }

    for (int c = 0; c < NCHUNK; ++c) {
        // Pack this chunk's candidates (register-only, pre-barrier).
        half8 plo0, phi0, plo1, phi1;
        packB(px0, py0, pz0, plo0, phi0);
        packB(px1, py1, pz1, plo1, phi1);
        __syncthreads();    // prev compute done: ldsB free
        {
            const int i0 = threadIdx.x;
            const int i1 = threadIdx.x + 512;
            *(half8*)&ldsB[(i0 >> 5) * 512 + (i0 & 31) * 8]       = plo0;
            *(half8*)&ldsB[(i0 >> 5) * 512 + 256 + (i0 & 31) * 8] = phi0;
            *(half8*)&ldsB[(i1 >> 5) * 512 + (i1 & 31) * 8]       = plo1;
            *(half8*)&ldsB[(i1 >> 5) * 512 + 256 + (i1 & 31) * 8] = phi1;
        }
        // Issue next chunk's raw loads now; latency hides under compute.
        if (c + 1 < NCHUNK) {
            const float* cp = Craw + (size_t)((c + 1) * CHUNK + threadIdx.x) * 3;
            px0 = cp[0]; py0 = cp[1]; pz0 = cp[2];
            const float* cq = Craw + (size_t)((c + 1) * CHUNK + 512 + threadIdx.x) * 3;
            px1 = cq[0]; py1 = cq[1]; pz1 = cq[2];
        }
        __syncthreads();    // ldsB ready

#pragma unroll
        for (int t = 0; t < CHUNK / 32; t += 2) {
            half8 bf0 = *(const half8*)&ldsB[ t      * 512 + lane * 8];
            half8 bf1 = *(const half8*)&ldsB[(t + 1) * 512 + lane * 8];
            f16x acc00 = __builtin_amdgcn_mfma_f32_32x32x16_f16(afrag0, bf0, zacc, 0, 0, 0);
            f16x acc01 = __builtin_amdgcn_mfma_f32_32x32x16_f16(afrag0, bf1, zacc, 0, 0, 0);
            f16x acc10 = __builtin_amdgcn_mfma_f32_32x32x16_f16(afrag1, bf0, zacc, 0, 0, 0);
            f16x acc11 = __builtin_amdgcn_mfma_f32_32x32x16_f16(afrag1, bf1, zacc, 0, 0, 0);

            // row-min: per-reg running min across cols.
#pragma unroll
            for (int r = 0; r < 16; ++r) {
                MN1a[r] = fminf(fminf(acc00[r], acc01[r]), MN1a[r]);
                MN1b[r] = fminf(fminf(acc10[r], acc11[r]), MN1b[r]);
            }
        }
    }

    // Butterfly min across the 32 cols of each half, lane 0 of each half
    // writes its rows: row = (r&3) + 8*(r>>2) + 4*half (+32 for the b set).
#pragma unroll
    for (int m = 1; m <= 16; m <<= 1)
#pragma unroll
        for (int r = 0; r < 16; ++r) {
            MN1a[r] = fminf(MN1a[r], __shfl_xor(MN1a[r], m, 64));
            MN1b[r] = fminf(MN1b[r], __shfl_xor(MN1b[r], m, 64));
        }
    if (col == 0) {
        float* o = minp + (((size_t)pass * B + b) * MH + mh) * NPTS + nbase;
#pragma unroll
        for (int r = 0; r < 16; ++r) {
            o[(r & 3) + 8 * (r >> 2) + 4 * half]      = MN1a[r];
            o[32 + (r & 3) + 8 * (r >> 2) + 4 * half] = MN1b[r];
        }
    }
}

// One thread per 4 rows: fold MH planes from each pass (float4), clamp,
// sum, wave-reduce, atomicAdd(out, sum/TOTAL).
__global__ __launch_bounds__(64) void reduce_kernel(
    const float* __restrict__ minp, float* __restrict__ out)
{
    int g  = blockIdx.x * 64 + threadIdx.x;       // [0, TOTAL/4)
    int b  = g >> 11;
    int mq = g & 2047;                            // float4 index within batch

    float v = 0.0f;
#pragma unroll
    for (int p = 0; p < 2; ++p) {
        const float4* pp =
            (const float4*)(minp + (((size_t)p * B + b) * MH) * NPTS) + mq;
        float4 a = pp[0];
#pragma unroll
        for (int s = 1; s < MH; ++s) {
            float4 t = pp[(size_t)s * (NPTS / 4)];
            a.x = fminf(a.x, t.x); a.y = fminf(a.y, t.y);
            a.z = fminf(a.z, t.z); a.w = fminf(a.w, t.w);
        }
        v += fmaxf(a.x, 0.0f) + fmaxf(a.y, 0.0f)
           + fmaxf(a.z, 0.0f) + fmaxf(a.w, 0.0f);
    }

#pragma unroll
    for (int off = 32; off; off >>= 1)
        v += __shfl_down(v, off, 64);
    if (threadIdx.x == 0)
        atomicAdd(out, v * (1.0f / (float)TOTAL));
}

extern "C" void kernel_launch(void* const* d_in, const int* in_sizes, int n_in,
                              void* d_out, int out_size, void* d_ws, size_t ws_size,
                              hipStream_t stream)
{
    const float* in1 = (const float*)d_in[0];
    const float* in2 = (const float*)d_in[1];
    float* out = (float*)d_out;

    float* minp = (float*)d_ws;    // 2 passes * MH * TOTAL * 4 = 2 MiB

    nn_mfma<<<dim3(NSTRIPS, 2 * MH, B), 512, 0, stream>>>(
        in1, in2, minp, out);
    reduce_kernel<<<TOTAL / 4 / 64, 64, 0, stream>>>(minp, out);
}